// Round 1
// baseline (207.110 us; speedup 1.0000x reference)
//
#include <hip/hip_runtime.h>
#include <math.h>

#define H 16
#define DH 128
#define HID 2048
#define NB 64
#define LCACHE 4096
#define NS 16
#define KSPLIT 4
#define SCALE 0.08838834764831845f

// ---------------- projection GEMM (M=64, K=2048, N=NC1+NC2), K-split partials ----------------
__global__ __launch_bounds__(256, 2) void proj_partial(
    const float* __restrict__ A, const float* __restrict__ W1, const float* __restrict__ W2,
    float* __restrict__ part, int NC1, int NC2) {
  const int NC = NC1 + NC2;
  const int c0 = blockIdx.x * 16;
  const int kLen = HID / KSPLIT;  // 512
  const int k0 = blockIdx.y * kLen;
  __shared__ float A_lds[64 * 68];
  const int t = threadIdx.x;
  const int cq = t & 3;
  const int row = t >> 2;
  const int col = c0 + cq * 4;
  float acc0 = 0.f, acc1 = 0.f, acc2 = 0.f, acc3 = 0.f;
  const float* Wp;
  int ldw, wcol;
  if (col < NC1) { Wp = W1; ldw = NC1; wcol = col; }
  else           { Wp = W2; ldw = NC2; wcol = col - NC1; }
  for (int kc = 0; kc < kLen; kc += 64) {
#pragma unroll
    for (int j = 0; j < 4; ++j) {
      const int f = t * 4 + 1024 * j;
      const int r = f >> 6;
      const int c = f & 63;
      *(float4*)&A_lds[r * 68 + c] = *(const float4*)(A + (size_t)r * HID + k0 + kc + c);
    }
    __syncthreads();
#pragma unroll 4
    for (int kk = 0; kk < 64; kk += 4) {
      const float4 a4 = *(const float4*)&A_lds[row * 68 + kk];
      const float4 w0 = *(const float4*)(Wp + (size_t)(k0 + kc + kk + 0) * ldw + wcol);
      const float4 w1 = *(const float4*)(Wp + (size_t)(k0 + kc + kk + 1) * ldw + wcol);
      const float4 w2 = *(const float4*)(Wp + (size_t)(k0 + kc + kk + 2) * ldw + wcol);
      const float4 w3 = *(const float4*)(Wp + (size_t)(k0 + kc + kk + 3) * ldw + wcol);
      acc0 = fmaf(a4.x, w0.x, acc0); acc1 = fmaf(a4.x, w0.y, acc1);
      acc2 = fmaf(a4.x, w0.z, acc2); acc3 = fmaf(a4.x, w0.w, acc3);
      acc0 = fmaf(a4.y, w1.x, acc0); acc1 = fmaf(a4.y, w1.y, acc1);
      acc2 = fmaf(a4.y, w1.z, acc2); acc3 = fmaf(a4.y, w1.w, acc3);
      acc0 = fmaf(a4.z, w2.x, acc0); acc1 = fmaf(a4.z, w2.y, acc1);
      acc2 = fmaf(a4.z, w2.z, acc2); acc3 = fmaf(a4.z, w2.w, acc3);
      acc0 = fmaf(a4.w, w3.x, acc0); acc1 = fmaf(a4.w, w3.y, acc1);
      acc2 = fmaf(a4.w, w3.z, acc2); acc3 = fmaf(a4.w, w3.w, acc3);
    }
    __syncthreads();
  }
  float4 o; o.x = acc0; o.y = acc1; o.z = acc2; o.w = acc3;
  *(float4*)(part + ((size_t)blockIdx.y * 64 + row) * NC + col) = o;
}

__global__ __launch_bounds__(256) void proj_combine(
    const float* __restrict__ part, const float* __restrict__ b1, const float* __restrict__ b2,
    float* __restrict__ out1, float* __restrict__ out2, int NC1, int NC2) {
  const int NC = NC1 + NC2;
  const int f = (blockIdx.x * 256 + threadIdx.x) * 4;
  if (f >= 64 * NC) return;
  const int row = f / NC;
  const int c = f - row * NC;
  float4 s = *(const float4*)(part + (size_t)row * NC + c);
#pragma unroll
  for (int sp = 1; sp < KSPLIT; ++sp) {
    const float4 p = *(const float4*)(part + ((size_t)sp * 64 + row) * NC + c);
    s.x += p.x; s.y += p.y; s.z += p.z; s.w += p.w;
  }
  if (c < NC1) {
    const float4 bb = *(const float4*)(b1 + c);
    s.x += bb.x; s.y += bb.y; s.z += bb.z; s.w += bb.w;
    *(float4*)(out1 + (size_t)row * NC1 + c) = s;
  } else {
    const int cc = c - NC1;
    const float4 bb = *(const float4*)(b2 + cc);
    s.x += bb.x; s.y += bb.y; s.z += bb.z; s.w += bb.w;
    *(float4*)(out2 + (size_t)row * NC2 + cc) = s;
  }
}

// ---------------- flash-decoding attention split ----------------
__global__ __launch_bounds__(256, 2) void attn_split(
    const float* __restrict__ q_buf, const float* __restrict__ kv_buf,
    const float* __restrict__ key_cache, const float* __restrict__ value_cache,
    const int* __restrict__ lens,
    float* __restrict__ part_out, float* __restrict__ part_m, float* __restrict__ part_l) {
  const int b = blockIdx.y;
  const int sp = blockIdx.x;
  const int ctx = lens[b];
  const int n0 = (ctx * sp) / NS;
  const int n1 = (ctx * (sp + 1)) / NS;
  const int cnt = n1 - n0;
  const bool has_self = (sp == NS - 1);
  const int tot = cnt + (has_self ? 1 : 0);
  const int t = threadIdx.x;
  if (tot == 0) {
    if (t < H) {
      part_m[((size_t)b * NS + sp) * H + t] = -1e30f;
      part_l[((size_t)b * NS + sp) * H + t] = 0.f;
    }
    return;
  }
  __shared__ float q_s[H * 140];    // [h][dg*36 + (d&31)] skewed to spread dg over bank quads
  __shared__ float Sm[H * 260];     // scores / probabilities
  __shared__ float KV[64 * 128];    // XOR-swizzled K (pass1) then V (pass2)
  __shared__ float red[H * 17];
  __shared__ float mrow[H];

  // stage q (scaled)
  for (int idx = t; idx < HID; idx += 256) {
    const int h = idx >> 7;
    const int d = idx & 127;
    q_s[h * 140 + (d >> 5) * 36 + (d & 31)] = q_buf[(size_t)b * HID + idx] * SCALE;
  }
  __syncthreads();

  const int lane = t & 63;
  const int wv = t >> 6;
  const int rq = lane & 15;
  const int dg = lane >> 4;   // 0..3, owns d in [dg*32, dg*32+32)
  const int h0 = wv * 4;      // wave owns 4 heads
  const int sw = (rq & 7) << 2;

  // ---- pass 1: scores ----
  for (int c0 = 0; c0 < cnt; c0 += 64) {
    const int mrows = min(64, cnt - c0);
    for (int f = t * 4; f < mrows * 128; f += 1024) {
      const int r = f >> 7;
      const int w = f & 127;
      const float4 v = *(const float4*)(key_cache + ((size_t)b * LCACHE + n0 + c0 + r) * DH + w);
      *(float4*)&KV[r * 128 + (w ^ ((r & 7) << 2))] = v;
    }
    __syncthreads();
    float acc[4][4];
#pragma unroll
    for (int x = 0; x < 4; ++x)
#pragma unroll
      for (int y = 0; y < 4; ++y) acc[x][y] = 0.f;
#pragma unroll
    for (int dd = 0; dd < 32; dd += 4) {
      const int wbase = (dg * 32 + dd) ^ sw;
      const float4 kv0 = *(const float4*)&KV[(rq +  0) * 128 + wbase];
      const float4 kv1 = *(const float4*)&KV[(rq + 16) * 128 + wbase];
      const float4 kv2 = *(const float4*)&KV[(rq + 32) * 128 + wbase];
      const float4 kv3 = *(const float4*)&KV[(rq + 48) * 128 + wbase];
#pragma unroll
      for (int hh = 0; hh < 4; ++hh) {
        const float4 q4 = *(const float4*)&q_s[(h0 + hh) * 140 + dg * 36 + dd];
        acc[hh][0] = fmaf(q4.x, kv0.x, fmaf(q4.y, kv0.y, fmaf(q4.z, kv0.z, fmaf(q4.w, kv0.w, acc[hh][0]))));
        acc[hh][1] = fmaf(q4.x, kv1.x, fmaf(q4.y, kv1.y, fmaf(q4.z, kv1.z, fmaf(q4.w, kv1.w, acc[hh][1]))));
        acc[hh][2] = fmaf(q4.x, kv2.x, fmaf(q4.y, kv2.y, fmaf(q4.z, kv2.z, fmaf(q4.w, kv2.w, acc[hh][2]))));
        acc[hh][3] = fmaf(q4.x, kv3.x, fmaf(q4.y, kv3.y, fmaf(q4.z, kv3.z, fmaf(q4.w, kv3.w, acc[hh][3]))));
      }
    }
#pragma unroll
    for (int hh = 0; hh < 4; ++hh)
#pragma unroll
      for (int j = 0; j < 4; ++j) {
        float v = acc[hh][j];
        v += __shfl_xor(v, 16, 64);
        v += __shfl_xor(v, 32, 64);
        acc[hh][j] = v;
      }
#pragma unroll
    for (int j = 0; j < 4; ++j) {
      const int r = rq + 16 * j;
      if (r < mrows) {
        const float v = (dg == 0) ? acc[0][j] : (dg == 1) ? acc[1][j]
                       : (dg == 2) ? acc[2][j] : acc[3][j];
        Sm[(h0 + dg) * 260 + c0 + r] = v;
      }
    }
    __syncthreads();
  }

  // ---- self token score ----
  if (has_self) {
    if (t < 128) {
      const int h = t >> 3;
      const int seg = t & 7;
      float ps = 0.f;
#pragma unroll
      for (int dd = 0; dd < 16; ++dd) {
        const int d = seg * 16 + dd;
        ps += q_s[h * 140 + (d >> 5) * 36 + (d & 31)] * kv_buf[(size_t)b * 256 + d];
      }
      red[h * 8 + seg] = ps;
    }
    __syncthreads();
    if (t < H) {
      float s = 0.f;
#pragma unroll
      for (int seg = 0; seg < 8; ++seg) s += red[t * 8 + seg];
      Sm[t * 260 + cnt] = s;
    }
    __syncthreads();
  }

  // ---- softmax ----
  const int hX = t & 15;
  const int g = t >> 4;
  float mloc = -1e30f;
  for (int i = g; i < tot; i += 16) mloc = fmaxf(mloc, Sm[hX * 260 + i]);
  red[hX * 17 + g] = mloc;
  __syncthreads();
  if (t < H) {
    float mx = red[t * 17];
#pragma unroll
    for (int gg = 1; gg < 16; ++gg) mx = fmaxf(mx, red[t * 17 + gg]);
    mrow[t] = mx;
  }
  __syncthreads();
  const float mh = mrow[hX];
  float sloc = 0.f;
  for (int i = g; i < tot; i += 16) {
    const float e = __expf(Sm[hX * 260 + i] - mh);
    Sm[hX * 260 + i] = e;
    sloc += e;
  }
  red[hX * 17 + g] = sloc;
  __syncthreads();
  if (t < H) {
    float ls = 0.f;
#pragma unroll
    for (int gg = 0; gg < 16; ++gg) ls += red[t * 17 + gg];
    part_m[((size_t)b * NS + sp) * H + t] = mrow[t];
    part_l[((size_t)b * NS + sp) * H + t] = ls;
  }
  __syncthreads();

  // ---- pass 2: PV ----
  const int d0 = (t >> 4) * 8;
  float o0=0.f,o1=0.f,o2=0.f,o3=0.f,o4=0.f,o5=0.f,o6=0.f,o7=0.f;
  for (int c0 = 0; c0 < cnt; c0 += 64) {
    const int mrows = min(64, cnt - c0);
    for (int f = t * 4; f < mrows * 128; f += 1024) {
      const int r = f >> 7;
      const int w = f & 127;
      const float4 v = *(const float4*)(value_cache + ((size_t)b * LCACHE + n0 + c0 + r) * DH + w);
      *(float4*)&KV[r * 128 + (w ^ ((r & 7) << 2))] = v;
    }
    __syncthreads();
    for (int i = 0; i < mrows; ++i) {
      const float p = Sm[hX * 260 + c0 + i];
      const int swv = (i & 7) << 2;
      const float4 va = *(const float4*)&KV[i * 128 + (d0 ^ swv)];
      const float4 vb = *(const float4*)&KV[i * 128 + ((d0 + 4) ^ swv)];
      o0 = fmaf(p, va.x, o0); o1 = fmaf(p, va.y, o1);
      o2 = fmaf(p, va.z, o2); o3 = fmaf(p, va.w, o3);
      o4 = fmaf(p, vb.x, o4); o5 = fmaf(p, vb.y, o5);
      o6 = fmaf(p, vb.z, o6); o7 = fmaf(p, vb.w, o7);
    }
    __syncthreads();
  }
  if (has_self) {
    const float p = Sm[hX * 260 + cnt];
    const float4 va = *(const float4*)(kv_buf + (size_t)b * 256 + 128 + d0);
    const float4 vb = *(const float4*)(kv_buf + (size_t)b * 256 + 128 + d0 + 4);
    o0 = fmaf(p, va.x, o0); o1 = fmaf(p, va.y, o1);
    o2 = fmaf(p, va.z, o2); o3 = fmaf(p, va.w, o3);
    o4 = fmaf(p, vb.x, o4); o5 = fmaf(p, vb.y, o5);
    o6 = fmaf(p, vb.z, o6); o7 = fmaf(p, vb.w, o7);
  }
  float* dst = part_out + (((size_t)b * NS + sp) * H + hX) * DH + d0;
  float4 r1; r1.x = o0; r1.y = o1; r1.z = o2; r1.w = o3;
  float4 r2; r2.x = o4; r2.y = o5; r2.z = o6; r2.w = o7;
  *(float4*)dst = r1;
  *(float4*)(dst + 4) = r2;
}

// ---------------- merge flash-decoding splits ----------------
__global__ __launch_bounds__(256) void attn_combine(
    const float* __restrict__ part_out, const float* __restrict__ part_m,
    const float* __restrict__ part_l, float* __restrict__ ctx_buf) {
  const int b = blockIdx.x;
  const int t = threadIdx.x;
  const int h = t >> 4;
  const int d0 = (t & 15) * 8;
  float M = -1e30f;
#pragma unroll
  for (int sp = 0; sp < NS; ++sp)
    M = fmaxf(M, part_m[((size_t)b * NS + sp) * H + h]);
  float Lsum = 0.f;
  float o0=0.f,o1=0.f,o2=0.f,o3=0.f,o4=0.f,o5=0.f,o6=0.f,o7=0.f;
#pragma unroll
  for (int sp = 0; sp < NS; ++sp) {
    const float m = part_m[((size_t)b * NS + sp) * H + h];
    if (m < -1e29f) continue;
    const float w = __expf(m - M);
    Lsum += w * part_l[((size_t)b * NS + sp) * H + h];
    const float* src = part_out + (((size_t)b * NS + sp) * H + h) * DH + d0;
    const float4 a = *(const float4*)src;
    const float4 c = *(const float4*)(src + 4);
    o0 = fmaf(w, a.x, o0); o1 = fmaf(w, a.y, o1);
    o2 = fmaf(w, a.z, o2); o3 = fmaf(w, a.w, o3);
    o4 = fmaf(w, c.x, o4); o5 = fmaf(w, c.y, o5);
    o6 = fmaf(w, c.z, o6); o7 = fmaf(w, c.w, o7);
  }
  const float inv = 1.f / Lsum;
  float* dst = ctx_buf + (size_t)b * HID + h * DH + d0;
  float4 r1; r1.x = o0*inv; r1.y = o1*inv; r1.z = o2*inv; r1.w = o3*inv;
  float4 r2; r2.x = o4*inv; r2.y = o5*inv; r2.z = o6*inv; r2.w = o7*inv;
  *(float4*)dst = r1;
  *(float4*)(dst + 4) = r2;
}

extern "C" void kernel_launch(void* const* d_in, const int* in_sizes, int n_in,
                              void* d_out, int out_size, void* d_ws, size_t ws_size,
                              hipStream_t stream) {
  const float* hidden      = (const float*)d_in[0];
  const float* key_cache   = (const float*)d_in[1];
  const float* value_cache = (const float*)d_in[2];
  const float* Wq  = (const float*)d_in[3];
  const float* bq  = (const float*)d_in[4];
  const float* Wkv = (const float*)d_in[5];
  const float* bkv = (const float*)d_in[6];
  const float* Wo  = (const float*)d_in[7];
  const float* bo  = (const float*)d_in[8];
  const int*   lens = (const int*)d_in[9];
  float* out = (float*)d_out;

  float* ws = (float*)d_ws;
  float* part1    = ws;                                   // KSPLIT*64*2304
  float* q_buf    = part1 + (size_t)KSPLIT * 64 * 2304;   // 64*2048
  float* kv_buf   = q_buf + (size_t)64 * HID;             // 64*256
  float* part_out = kv_buf + (size_t)64 * 256;            // 64*NS*H*DH
  float* part_m   = part_out + (size_t)64 * NS * H * DH;  // 64*NS*H
  float* part_l   = part_m + (size_t)64 * NS * H;         // 64*NS*H
  float* ctx_buf  = part_l + (size_t)64 * NS * H;         // 64*2048
  float* part2    = ctx_buf + (size_t)64 * HID;           // KSPLIT*64*2048

  proj_partial<<<dim3(144, KSPLIT), dim3(256), 0, stream>>>(hidden, Wq, Wkv, part1, 2048, 256);
  proj_combine<<<dim3(144), dim3(256), 0, stream>>>(part1, bq, bkv, q_buf, kv_buf, 2048, 256);
  attn_split<<<dim3(NS, NB), dim3(256), 0, stream>>>(q_buf, kv_buf, key_cache, value_cache,
                                                     lens, part_out, part_m, part_l);
  attn_combine<<<dim3(NB), dim3(256), 0, stream>>>(part_out, part_m, part_l, ctx_buf);
  proj_partial<<<dim3(128, KSPLIT), dim3(256), 0, stream>>>(ctx_buf, Wo, Wo, part2, 2048, 0);
  proj_combine<<<dim3(128), dim3(256), 0, stream>>>(part2, bo, bo, out, nullptr, 2048, 0);
}

// Round 2
// 169.125 us; speedup vs baseline: 1.2246x; 1.2246x over previous
//
#include <hip/hip_runtime.h>
#include <math.h>

#define H 16
#define DH 128
#define HID 2048
#define NB 64
#define LCACHE 4096
#define KSPLIT 4
#define SCALE 0.08838834764831845f

// ---------------- projection GEMM (M=64, K=2048, N=NC1+NC2), K-split partials ----------------
__global__ __launch_bounds__(256, 2) void proj_partial(
    const float* __restrict__ A, const float* __restrict__ W1, const float* __restrict__ W2,
    float* __restrict__ part, int NC1, int NC2) {
  const int NC = NC1 + NC2;
  const int c0 = blockIdx.x * 16;
  const int kLen = HID / KSPLIT;  // 512
  const int k0 = blockIdx.y * kLen;
  __shared__ float A_lds[64 * 68];
  const int t = threadIdx.x;
  const int cq = t & 3;
  const int row = t >> 2;
  const int col = c0 + cq * 4;
  float acc0 = 0.f, acc1 = 0.f, acc2 = 0.f, acc3 = 0.f;
  const float* Wp;
  int ldw, wcol;
  if (col < NC1) { Wp = W1; ldw = NC1; wcol = col; }
  else           { Wp = W2; ldw = NC2; wcol = col - NC1; }
  for (int kc = 0; kc < kLen; kc += 64) {
#pragma unroll
    for (int j = 0; j < 4; ++j) {
      const int f = t * 4 + 1024 * j;
      const int r = f >> 6;
      const int c = f & 63;
      *(float4*)&A_lds[r * 68 + c] = *(const float4*)(A + (size_t)r * HID + k0 + kc + c);
    }
    __syncthreads();
#pragma unroll 4
    for (int kk = 0; kk < 64; kk += 4) {
      const float4 a4 = *(const float4*)&A_lds[row * 68 + kk];
      const float4 w0 = *(const float4*)(Wp + (size_t)(k0 + kc + kk + 0) * ldw + wcol);
      const float4 w1 = *(const float4*)(Wp + (size_t)(k0 + kc + kk + 1) * ldw + wcol);
      const float4 w2 = *(const float4*)(Wp + (size_t)(k0 + kc + kk + 2) * ldw + wcol);
      const float4 w3 = *(const float4*)(Wp + (size_t)(k0 + kc + kk + 3) * ldw + wcol);
      acc0 = fmaf(a4.x, w0.x, acc0); acc1 = fmaf(a4.x, w0.y, acc1);
      acc2 = fmaf(a4.x, w0.z, acc2); acc3 = fmaf(a4.x, w0.w, acc3);
      acc0 = fmaf(a4.y, w1.x, acc0); acc1 = fmaf(a4.y, w1.y, acc1);
      acc2 = fmaf(a4.y, w1.z, acc2); acc3 = fmaf(a4.y, w1.w, acc3);
      acc0 = fmaf(a4.z, w2.x, acc0); acc1 = fmaf(a4.z, w2.y, acc1);
      acc2 = fmaf(a4.z, w2.z, acc2); acc3 = fmaf(a4.z, w2.w, acc3);
      acc0 = fmaf(a4.w, w3.x, acc0); acc1 = fmaf(a4.w, w3.y, acc1);
      acc2 = fmaf(a4.w, w3.z, acc2); acc3 = fmaf(a4.w, w3.w, acc3);
    }
    __syncthreads();
  }
  float4 o; o.x = acc0; o.y = acc1; o.z = acc2; o.w = acc3;
  *(float4*)(part + ((size_t)blockIdx.y * 64 + row) * NC + col) = o;
}

__global__ __launch_bounds__(256) void proj_combine(
    const float* __restrict__ part, const float* __restrict__ b1, const float* __restrict__ b2,
    float* __restrict__ out1, float* __restrict__ out2, int NC1, int NC2) {
  const int NC = NC1 + NC2;
  const int f = (blockIdx.x * 256 + threadIdx.x) * 4;
  if (f >= 64 * NC) return;
  const int row = f / NC;
  const int c = f - row * NC;
  float4 s = *(const float4*)(part + (size_t)row * NC + c);
#pragma unroll
  for (int sp = 1; sp < KSPLIT; ++sp) {
    const float4 p = *(const float4*)(part + ((size_t)sp * 64 + row) * NC + c);
    s.x += p.x; s.y += p.y; s.z += p.z; s.w += p.w;
  }
  if (c < NC1) {
    const float4 bb = *(const float4*)(b1 + c);
    s.x += bb.x; s.y += bb.y; s.z += bb.z; s.w += bb.w;
    *(float4*)(out1 + (size_t)row * NC1 + c) = s;
  } else {
    const int cc = c - NC1;
    const float4 bb = *(const float4*)(b2 + cc);
    s.x += bb.x; s.y += bb.y; s.z += bb.z; s.w += bb.w;
    *(float4*)(out2 + (size_t)row * NC2 + cc) = s;
  }
}

// ---------------- flash-decoding attention split (pipelined, 32-row tiles) ----------------
template <int NSPLIT>
__global__ __launch_bounds__(256, 3) void attn_split(
    const float* __restrict__ q_buf, const float* __restrict__ kv_buf,
    const float* __restrict__ key_cache, const float* __restrict__ value_cache,
    const int* __restrict__ lens,
    float* __restrict__ part_out, float* __restrict__ part_m, float* __restrict__ part_l) {
  const int b = blockIdx.y;
  const int sp = blockIdx.x;
  const int ctx = lens[b];
  const int n0 = (ctx * sp) / NSPLIT;
  const int n1 = (ctx * (sp + 1)) / NSPLIT;
  const int cnt = n1 - n0;
  const bool has_self = (sp == NSPLIT - 1);
  const int tot = cnt + (has_self ? 1 : 0);
  const int t = threadIdx.x;
  if (tot == 0) {
    if (t < H) {
      part_m[((size_t)b * NSPLIT + sp) * H + t] = -1e30f;
      part_l[((size_t)b * NSPLIT + sp) * H + t] = 0.f;
    }
    return;
  }
  __shared__ float KV[2][32 * 128];  // double-buffered, XOR-swizzled tiles
  __shared__ float Sm[H * 132];      // scores / probabilities (NSPLIT>=32 -> tot<=129)
  __shared__ float q_s[H * 140];     // [h][dg*36 + (d&31)]
  __shared__ float red[H * 17];
  __shared__ float mrow[H];

  // stage q (scaled)
  for (int idx = t; idx < HID; idx += 256) {
    const int h = idx >> 7;
    const int d = idx & 127;
    q_s[h * 140 + (d >> 5) * 36 + (d & 31)] = q_buf[(size_t)b * HID + idx] * SCALE;
  }

  const int lane = t & 63;
  const int wv = t >> 6;
  const int rq = lane & 15;
  const int dg = lane >> 4;
  const int h0 = wv * 4;
  const int sw = (rq & 7) << 2;
  const int f0 = t * 16;            // this thread's 16-float staging chunk
  const int ntiles = (cnt + 31) >> 5;
  const float* ksrc = key_cache + ((size_t)b * LCACHE + n0) * DH;
  const float* vsrc = value_cache + ((size_t)b * LCACHE + n0) * DH;

  // prologue: stage K tile 0
  if (ntiles > 0) {
    const int mr = min(32, cnt);
    if (f0 < mr * 128) {
      const float4 g0 = *(const float4*)(ksrc + f0);
      const float4 g1 = *(const float4*)(ksrc + f0 + 4);
      const float4 g2 = *(const float4*)(ksrc + f0 + 8);
      const float4 g3 = *(const float4*)(ksrc + f0 + 12);
      const int r = f0 >> 7, w = f0 & 127, s2 = (r & 7) << 2;
      float* dst = &KV[0][r * 128];
      *(float4*)&dst[(w + 0) ^ s2] = g0;
      *(float4*)&dst[(w + 4) ^ s2] = g1;
      *(float4*)&dst[(w + 8) ^ s2] = g2;
      *(float4*)&dst[(w + 12) ^ s2] = g3;
    }
  }
  __syncthreads();

  // ---- pass 1: scores (pipelined) ----
  for (int tt = 0; tt < ntiles; ++tt) {
    const int mrows = min(32, cnt - tt * 32);
    // issue next-tile loads early (latency hides under compute)
    float4 g0, g1, g2, g3;
    bool ldn = false;
    if (tt + 1 < ntiles) {
      const int mr = min(32, cnt - (tt + 1) * 32);
      if (f0 < mr * 128) {
        ldn = true;
        const float* s = ksrc + (size_t)(tt + 1) * 32 * DH;
        g0 = *(const float4*)(s + f0);
        g1 = *(const float4*)(s + f0 + 4);
        g2 = *(const float4*)(s + f0 + 8);
        g3 = *(const float4*)(s + f0 + 12);
      }
    }
    const float* bufc = KV[tt & 1];
    float acc[4][2];
#pragma unroll
    for (int x = 0; x < 4; ++x) { acc[x][0] = 0.f; acc[x][1] = 0.f; }
#pragma unroll
    for (int dd = 0; dd < 32; dd += 4) {
      const int wb = (dg * 32 + dd) ^ sw;
      const float4 k0 = *(const float4*)&bufc[rq * 128 + wb];
      const float4 k1 = *(const float4*)&bufc[(rq + 16) * 128 + wb];
#pragma unroll
      for (int hh = 0; hh < 4; ++hh) {
        const float4 q4 = *(const float4*)&q_s[(h0 + hh) * 140 + dg * 36 + dd];
        acc[hh][0] = fmaf(q4.x, k0.x, fmaf(q4.y, k0.y, fmaf(q4.z, k0.z, fmaf(q4.w, k0.w, acc[hh][0]))));
        acc[hh][1] = fmaf(q4.x, k1.x, fmaf(q4.y, k1.y, fmaf(q4.z, k1.z, fmaf(q4.w, k1.w, acc[hh][1]))));
      }
    }
#pragma unroll
    for (int hh = 0; hh < 4; ++hh)
#pragma unroll
      for (int j = 0; j < 2; ++j) {
        float v = acc[hh][j];
        v += __shfl_xor(v, 16, 64);
        v += __shfl_xor(v, 32, 64);
        acc[hh][j] = v;
      }
#pragma unroll
    for (int j = 0; j < 2; ++j) {
      const int r = rq + 16 * j;
      if (r < mrows) {
        const float v = (dg == 0) ? acc[0][j] : (dg == 1) ? acc[1][j]
                       : (dg == 2) ? acc[2][j] : acc[3][j];
        Sm[(h0 + dg) * 132 + tt * 32 + r] = v;
      }
    }
    if (ldn) {
      const int r = f0 >> 7, w = f0 & 127, s2 = (r & 7) << 2;
      float* dst = &KV[(tt + 1) & 1][r * 128];
      *(float4*)&dst[(w + 0) ^ s2] = g0;
      *(float4*)&dst[(w + 4) ^ s2] = g1;
      *(float4*)&dst[(w + 8) ^ s2] = g2;
      *(float4*)&dst[(w + 12) ^ s2] = g3;
    }
    __syncthreads();
  }

  // issue V tile 0 loads now; they fly during self-token + softmax
  float4 v0_, v1_, v2_, v3_;
  bool ldv = false;
  if (ntiles > 0) {
    const int mr = min(32, cnt);
    if (f0 < mr * 128) {
      ldv = true;
      v0_ = *(const float4*)(vsrc + f0);
      v1_ = *(const float4*)(vsrc + f0 + 4);
      v2_ = *(const float4*)(vsrc + f0 + 8);
      v3_ = *(const float4*)(vsrc + f0 + 12);
    }
  }

  // ---- self token score ----
  if (has_self) {
    if (t < 128) {
      const int h = t >> 3;
      const int seg = t & 7;
      float ps = 0.f;
#pragma unroll
      for (int dd = 0; dd < 16; ++dd) {
        const int d = seg * 16 + dd;
        ps += q_s[h * 140 + (d >> 5) * 36 + (d & 31)] * kv_buf[(size_t)b * 256 + d];
      }
      red[h * 8 + seg] = ps;
    }
    __syncthreads();
    if (t < H) {
      float s = 0.f;
#pragma unroll
      for (int seg = 0; seg < 8; ++seg) s += red[t * 8 + seg];
      Sm[t * 132 + cnt] = s;
    }
  }
  __syncthreads();

  // ---- softmax ----
  const int hX = t & 15;
  const int g = t >> 4;
  float mloc = -1e30f;
  for (int i = g; i < tot; i += 16) mloc = fmaxf(mloc, Sm[hX * 132 + i]);
  red[hX * 17 + g] = mloc;
  __syncthreads();
  if (t < H) {
    float mx = red[t * 17];
#pragma unroll
    for (int gg = 1; gg < 16; ++gg) mx = fmaxf(mx, red[t * 17 + gg]);
    mrow[t] = mx;
  }
  __syncthreads();
  const float mh = mrow[hX];
  float sloc = 0.f;
  for (int i = g; i < tot; i += 16) {
    const float e = __expf(Sm[hX * 132 + i] - mh);
    Sm[hX * 132 + i] = e;
    sloc += e;
  }
  red[hX * 17 + g] = sloc;
  __syncthreads();
  if (t < H) {
    float ls = 0.f;
#pragma unroll
    for (int gg = 0; gg < 16; ++gg) ls += red[t * 17 + gg];
    part_m[((size_t)b * NSPLIT + sp) * H + t] = mrow[t];
    part_l[((size_t)b * NSPLIT + sp) * H + t] = ls;
  }
  __syncthreads();

  // write prefetched V tile 0
  if (ldv) {
    const int r = f0 >> 7, w = f0 & 127, s2 = (r & 7) << 2;
    float* dst = &KV[0][r * 128];
    *(float4*)&dst[(w + 0) ^ s2] = v0_;
    *(float4*)&dst[(w + 4) ^ s2] = v1_;
    *(float4*)&dst[(w + 8) ^ s2] = v2_;
    *(float4*)&dst[(w + 12) ^ s2] = v3_;
  }
  __syncthreads();

  // ---- pass 2: PV (pipelined) ----
  const int d0 = (t >> 4) * 8;
  float o0=0.f,o1=0.f,o2=0.f,o3=0.f,o4=0.f,o5=0.f,o6=0.f,o7=0.f;
  for (int tt = 0; tt < ntiles; ++tt) {
    const int mrows = min(32, cnt - tt * 32);
    float4 g0, g1, g2, g3;
    bool ldn = false;
    if (tt + 1 < ntiles) {
      const int mr = min(32, cnt - (tt + 1) * 32);
      if (f0 < mr * 128) {
        ldn = true;
        const float* s = vsrc + (size_t)(tt + 1) * 32 * DH;
        g0 = *(const float4*)(s + f0);
        g1 = *(const float4*)(s + f0 + 4);
        g2 = *(const float4*)(s + f0 + 8);
        g3 = *(const float4*)(s + f0 + 12);
      }
    }
    const float* bufc = KV[tt & 1];
#pragma unroll 4
    for (int i = 0; i < mrows; ++i) {
      const float p = Sm[hX * 132 + tt * 32 + i];
      const int swv = (i & 7) << 2;
      const float4 va = *(const float4*)&bufc[i * 128 + (d0 ^ swv)];
      const float4 vb = *(const float4*)&bufc[i * 128 + ((d0 + 4) ^ swv)];
      o0 = fmaf(p, va.x, o0); o1 = fmaf(p, va.y, o1);
      o2 = fmaf(p, va.z, o2); o3 = fmaf(p, va.w, o3);
      o4 = fmaf(p, vb.x, o4); o5 = fmaf(p, vb.y, o5);
      o6 = fmaf(p, vb.z, o6); o7 = fmaf(p, vb.w, o7);
    }
    if (ldn) {
      const int r = f0 >> 7, w = f0 & 127, s2 = (r & 7) << 2;
      float* dst = &KV[(tt + 1) & 1][r * 128];
      *(float4*)&dst[(w + 0) ^ s2] = g0;
      *(float4*)&dst[(w + 4) ^ s2] = g1;
      *(float4*)&dst[(w + 8) ^ s2] = g2;
      *(float4*)&dst[(w + 12) ^ s2] = g3;
    }
    __syncthreads();
  }
  if (has_self) {
    const float p = Sm[hX * 132 + cnt];
    const float4 va = *(const float4*)(kv_buf + (size_t)b * 256 + 128 + d0);
    const float4 vb = *(const float4*)(kv_buf + (size_t)b * 256 + 128 + d0 + 4);
    o0 = fmaf(p, va.x, o0); o1 = fmaf(p, va.y, o1);
    o2 = fmaf(p, va.z, o2); o3 = fmaf(p, va.w, o3);
    o4 = fmaf(p, vb.x, o4); o5 = fmaf(p, vb.y, o5);
    o6 = fmaf(p, vb.z, o6); o7 = fmaf(p, vb.w, o7);
  }
  float* dst = part_out + (((size_t)b * NSPLIT + sp) * H + hX) * DH + d0;
  float4 r1; r1.x = o0; r1.y = o1; r1.z = o2; r1.w = o3;
  float4 r2; r2.x = o4; r2.y = o5; r2.z = o6; r2.w = o7;
  *(float4*)dst = r1;
  *(float4*)(dst + 4) = r2;
}

// ---------------- merge flash-decoding splits ----------------
template <int NSPLIT>
__global__ __launch_bounds__(256) void attn_combine(
    const float* __restrict__ part_out, const float* __restrict__ part_m,
    const float* __restrict__ part_l, float* __restrict__ ctx_buf) {
  const int b = blockIdx.x;
  const int t = threadIdx.x;
  const int h = t >> 4;
  const int d0 = (t & 15) * 8;
  float M = -1e30f;
#pragma unroll
  for (int sp = 0; sp < NSPLIT; ++sp)
    M = fmaxf(M, part_m[((size_t)b * NSPLIT + sp) * H + h]);
  float Lsum = 0.f;
  float o0=0.f,o1=0.f,o2=0.f,o3=0.f,o4=0.f,o5=0.f,o6=0.f,o7=0.f;
#pragma unroll
  for (int sp = 0; sp < NSPLIT; ++sp) {
    const float m = part_m[((size_t)b * NSPLIT + sp) * H + h];
    if (m < -1e29f) continue;
    const float w = __expf(m - M);
    Lsum += w * part_l[((size_t)b * NSPLIT + sp) * H + h];
    const float* src = part_out + (((size_t)b * NSPLIT + sp) * H + h) * DH + d0;
    const float4 a = *(const float4*)src;
    const float4 c = *(const float4*)(src + 4);
    o0 = fmaf(w, a.x, o0); o1 = fmaf(w, a.y, o1);
    o2 = fmaf(w, a.z, o2); o3 = fmaf(w, a.w, o3);
    o4 = fmaf(w, c.x, o4); o5 = fmaf(w, c.y, o5);
    o6 = fmaf(w, c.z, o6); o7 = fmaf(w, c.w, o7);
  }
  const float inv = 1.f / Lsum;
  float* dst = ctx_buf + (size_t)b * HID + h * DH + d0;
  float4 r1; r1.x = o0*inv; r1.y = o1*inv; r1.z = o2*inv; r1.w = o3*inv;
  float4 r2; r2.x = o4*inv; r2.y = o5*inv; r2.z = o6*inv; r2.w = o7*inv;
  *(float4*)dst = r1;
  *(float4*)(dst + 4) = r2;
}

extern "C" void kernel_launch(void* const* d_in, const int* in_sizes, int n_in,
                              void* d_out, int out_size, void* d_ws, size_t ws_size,
                              hipStream_t stream) {
  const float* hidden      = (const float*)d_in[0];
  const float* key_cache   = (const float*)d_in[1];
  const float* value_cache = (const float*)d_in[2];
  const float* Wq  = (const float*)d_in[3];
  const float* bq  = (const float*)d_in[4];
  const float* Wkv = (const float*)d_in[5];
  const float* bkv = (const float*)d_in[6];
  const float* Wo  = (const float*)d_in[7];
  const float* bo  = (const float*)d_in[8];
  const int*   lens = (const int*)d_in[9];
  float* out = (float*)d_out;

  // choose split count by workspace capacity (deterministic)
  const size_t fixed = (size_t)KSPLIT * 64 * 2304 + (size_t)64 * HID + (size_t)64 * 256 +
                       (size_t)64 * HID + (size_t)KSPLIT * 64 * 2048;
  const size_t need32 = (fixed + (size_t)64 * 32 * H * DH + 2 * (size_t)64 * 32 * H) * 4;
  const int ns = (ws_size >= need32) ? 32 : 16;

  float* ws = (float*)d_ws;
  float* part1    = ws;                                    // KSPLIT*64*2304
  float* q_buf    = part1 + (size_t)KSPLIT * 64 * 2304;    // 64*2048
  float* kv_buf   = q_buf + (size_t)64 * HID;              // 64*256
  float* part_out = kv_buf + (size_t)64 * 256;             // 64*ns*H*DH
  float* part_m   = part_out + (size_t)64 * ns * H * DH;   // 64*ns*H
  float* part_l   = part_m + (size_t)64 * ns * H;          // 64*ns*H
  float* ctx_buf  = part_l + (size_t)64 * ns * H;          // 64*2048
  float* part2    = ctx_buf + (size_t)64 * HID;            // KSPLIT*64*2048

  proj_partial<<<dim3(144, KSPLIT), dim3(256), 0, stream>>>(hidden, Wq, Wkv, part1, 2048, 256);
  proj_combine<<<dim3(144), dim3(256), 0, stream>>>(part1, bq, bkv, q_buf, kv_buf, 2048, 256);
  if (ns == 32) {
    attn_split<32><<<dim3(32, NB), dim3(256), 0, stream>>>(q_buf, kv_buf, key_cache, value_cache,
                                                           lens, part_out, part_m, part_l);
    attn_combine<32><<<dim3(NB), dim3(256), 0, stream>>>(part_out, part_m, part_l, ctx_buf);
  } else {
    attn_split<16><<<dim3(16, NB), dim3(256), 0, stream>>>(q_buf, kv_buf, key_cache, value_cache,
                                                           lens, part_out, part_m, part_l);
    attn_combine<16><<<dim3(NB), dim3(256), 0, stream>>>(part_out, part_m, part_l, ctx_buf);
  }
  proj_partial<<<dim3(128, KSPLIT), dim3(256), 0, stream>>>(ctx_buf, Wo, Wo, part2, 2048, 0);
  proj_combine<<<dim3(128), dim3(256), 0, stream>>>(part2, bo, bo, out, nullptr, 2048, 0);
}

// Round 3
// 107.617 us; speedup vs baseline: 1.9245x; 1.5716x over previous
//
#include <hip/hip_runtime.h>
#include <hip/hip_bf16.h>
#include <math.h>

#define H 16
#define DH 128
#define HID 2048
#define NB 64
#define LCACHE 4096
#define NS 16
#define NKS 16
#define SCALE 0.08838834764831845f

typedef __attribute__((ext_vector_type(8))) short bf16x8;
typedef __attribute__((ext_vector_type(4))) float f32x4;

static __device__ inline unsigned short bfr(float x) {
  union { __hip_bfloat16 b; unsigned short u; } c;
  c.b = __float2bfloat16(x);
  return c.u;
}
static __device__ inline unsigned pkbf(float lo, float hi) {
  return (unsigned)bfr(lo) | ((unsigned)bfr(hi) << 16);
}
union BFU { unsigned u[4]; bf16x8 v; };

// ---------------- transpose A[64][2048] -> At[2048][64] ----------------
__global__ __launch_bounds__(256) void transpose64(const float* __restrict__ A,
                                                   float* __restrict__ At) {
  __shared__ float tile[64 * 65];
  const int k0 = blockIdx.x * 64;
  for (int idx = threadIdx.x; idx < 4096; idx += 256) {
    const int m = idx >> 6, c = idx & 63;
    tile[c * 65 + m] = A[(size_t)m * HID + k0 + c];
  }
  __syncthreads();
  for (int idx = threadIdx.x; idx < 4096; idx += 256) {
    const int c = idx >> 6, m = idx & 63;
    At[(size_t)(k0 + c) * 64 + m] = tile[c * 65 + m];
  }
}

// ---------------- projection: outer-product, W streamed once ----------------
// grid (NC/128, 16); block 256; per-thread 4m x 8n acc
__global__ __launch_bounds__(256, 4) void proj_v2(
    const float* __restrict__ At, const float* __restrict__ W1, const float* __restrict__ W2,
    float* __restrict__ part, int NC1, int NC2) {
  const int NC = NC1 + NC2;
  const int n0 = blockIdx.x * 128;
  const int k0 = blockIdx.y * 128;
  __shared__ float Asub[128 * 68];
  const int t = threadIdx.x;
#pragma unroll
  for (int j = 0; j < 8; ++j) {
    const int f = t * 4 + j * 1024;
    const int k = f >> 6, m = f & 63;
    *(float4*)&Asub[k * 68 + m] = *(const float4*)(At + (size_t)(k0 + k) * 64 + m);
  }
  __syncthreads();
  const int m0 = (t & 15) * 4;
  const int ng = (t >> 4) * 8;
  const float* Wp;
  int ldw, wc;
  if (n0 + ng < NC1) { Wp = W1; ldw = NC1; wc = n0 + ng; }
  else               { Wp = W2; ldw = NC2; wc = n0 + ng - NC1; }
  float acc[4][8];
#pragma unroll
  for (int i = 0; i < 4; ++i)
#pragma unroll
    for (int j = 0; j < 8; ++j) acc[i][j] = 0.f;
#pragma unroll 4
  for (int k = 0; k < 128; ++k) {
    const float4 a4 = *(const float4*)&Asub[k * 68 + m0];
    const float* wrow = Wp + (size_t)(k0 + k) * ldw + wc;
    const float4 w0 = *(const float4*)(wrow);
    const float4 w1 = *(const float4*)(wrow + 4);
    const float av[4] = {a4.x, a4.y, a4.z, a4.w};
    const float wv[8] = {w0.x, w0.y, w0.z, w0.w, w1.x, w1.y, w1.z, w1.w};
#pragma unroll
    for (int i = 0; i < 4; ++i)
#pragma unroll
      for (int j = 0; j < 8; ++j) acc[i][j] = fmaf(av[i], wv[j], acc[i][j]);
  }
#pragma unroll
  for (int i = 0; i < 4; ++i) {
    float4 o1, o2;
    o1.x = acc[i][0]; o1.y = acc[i][1]; o1.z = acc[i][2]; o1.w = acc[i][3];
    o2.x = acc[i][4]; o2.y = acc[i][5]; o2.z = acc[i][6]; o2.w = acc[i][7];
    float* dst = part + ((size_t)blockIdx.y * 64 + m0 + i) * NC + n0 + ng;
    *(float4*)dst = o1;
    *(float4*)(dst + 4) = o2;
  }
}

__global__ __launch_bounds__(256) void proj_combine(
    const float* __restrict__ part, const float* __restrict__ b1, const float* __restrict__ b2,
    float* __restrict__ out1, float* __restrict__ out2, int NC1, int NC2) {
  const int NC = NC1 + NC2;
  const int f = (blockIdx.x * 256 + threadIdx.x) * 4;
  if (f >= 64 * NC) return;
  const int row = f / NC;
  const int c = f - row * NC;
  float4 s = *(const float4*)(part + (size_t)row * NC + c);
#pragma unroll
  for (int sp = 1; sp < NKS; ++sp) {
    const float4 p = *(const float4*)(part + ((size_t)sp * 64 + row) * NC + c);
    s.x += p.x; s.y += p.y; s.z += p.z; s.w += p.w;
  }
  if (c < NC1) {
    const float4 bb = *(const float4*)(b1 + c);
    s.x += bb.x; s.y += bb.y; s.z += bb.z; s.w += bb.w;
    *(float4*)(out1 + (size_t)row * NC1 + c) = s;
  } else {
    const int cc = c - NC1;
    const float4 bb = *(const float4*)(b2 + cc);
    s.x += bb.x; s.y += bb.y; s.z += bb.z; s.w += bb.w;
    *(float4*)(out2 + (size_t)row * NC2 + cc) = s;
  }
}

// ---------------- MFMA flash-decoding attention split ----------------
template <int NSPLIT>
__global__ __launch_bounds__(256, 3) void attn_mfma(
    const float* __restrict__ q_buf, const float* __restrict__ kv_buf,
    const float* __restrict__ key_cache, const float* __restrict__ value_cache,
    const int* __restrict__ lens,
    float* __restrict__ part_out, float* __restrict__ part_m, float* __restrict__ part_l) {
  const int b = blockIdx.y;
  const int sp = blockIdx.x;
  const int ctx = lens[b];
  const int n0 = (ctx * sp) / NSPLIT;
  const int n1 = (ctx * (sp + 1)) / NSPLIT;
  const int cnt = n1 - n0;
  const bool has_self = (sp == NSPLIT - 1);
  const int tot = cnt + (has_self ? 1 : 0);
  const int t = threadIdx.x;
  if (tot == 0) {
    if (t < H) {
      part_m[((size_t)b * NSPLIT + sp) * H + t] = -1e30f;
      part_l[((size_t)b * NSPLIT + sp) * H + t] = 0.f;
    }
    return;
  }
  // region A: pass1 = q_s f32[16][132] (8448B) + Sm f32[16][259] (16576B); pass2 = Vt bf16[128][88]
  __shared__ __align__(16) char regA[25024];
  // region B: pass1 = K bf16[64][128] swizzled (16384B); pass2 = P bf16[16][264] (8448B)
  __shared__ __align__(16) char regB[16384];
  __shared__ float red[16 * 17];
  __shared__ float mrow[16];
  __shared__ float selfp[16];

  float* q_s = (float*)regA;
  float* Sm = (float*)(regA + 8448);
  unsigned short* Vt = (unsigned short*)regA;
  char* Kl = regB;
  char* P = regB;

  // stage q (scaled)
  for (int idx = t; idx < HID; idx += 256)
    q_s[(idx >> 7) * 132 + (idx & 127)] = q_buf[(size_t)b * HID + idx] * SCALE;

  const int lane = t & 63;
  const int wv = t >> 6;
  const int fh = lane & 15;    // mfma lane&15
  const int fg = lane >> 4;    // mfma k-group
  const int si = t & 63;       // K-staging row
  const int sc = t >> 6;       // K-staging d-chunk (32 floats)
  const int vp = t & 31;       // V-staging row pair
  const int vc = t >> 5;       // V-staging d-chunk (16 floats)
  const int ntiles = (cnt + 63) >> 6;
  const float* ksrc = key_cache + (size_t)b * LCACHE * DH;
  const float* vsrc = value_cache + (size_t)b * LCACHE * DH;

  float4 kst[8];
  // issue K tile 0 loads
  if (ntiles > 0) {
    const int r = min(n0 + si, LCACHE - 1);
    const float* src = ksrc + (size_t)r * DH + sc * 32;
#pragma unroll
    for (int j = 0; j < 8; ++j) kst[j] = *(const float4*)(src + j * 4);
  }
  __syncthreads();  // q_s ready

  // hoist q B-frags to registers
  bf16x8 qf[4];
#pragma unroll
  for (int s = 0; s < 4; ++s) {
    const float4 qa = *(const float4*)&q_s[fh * 132 + s * 32 + fg * 8];
    const float4 qb = *(const float4*)&q_s[fh * 132 + s * 32 + fg * 8 + 4];
    BFU u;
    u.u[0] = pkbf(qa.x, qa.y); u.u[1] = pkbf(qa.z, qa.w);
    u.u[2] = pkbf(qb.x, qb.y); u.u[3] = pkbf(qb.z, qb.w);
    qf[s] = u.v;
  }

  // ---- pass 1: scores via mfma(K, q) ----
  for (int tt = 0; tt < ntiles; ++tt) {
    if (tt > 0) __syncthreads();  // prior compute done
    // write staged K tile (bf16, XOR-swizzled 16B units)
#pragma unroll
    for (int s2 = 0; s2 < 4; ++s2) {
      BFU u;
      u.u[0] = pkbf(kst[s2 * 2].x, kst[s2 * 2].y);
      u.u[1] = pkbf(kst[s2 * 2].z, kst[s2 * 2].w);
      u.u[2] = pkbf(kst[s2 * 2 + 1].x, kst[s2 * 2 + 1].y);
      u.u[3] = pkbf(kst[s2 * 2 + 1].z, kst[s2 * 2 + 1].w);
      const int off = si * 256 + ((sc * 64 + s2 * 16) ^ ((si & 7) << 4));
      *(bf16x8*)(Kl + off) = u.v;
    }
    if (tt + 1 < ntiles) {
      const int r = min(n0 + (tt + 1) * 64 + si, LCACHE - 1);
      const float* src = ksrc + (size_t)r * DH + sc * 32;
#pragma unroll
      for (int j = 0; j < 8; ++j) kst[j] = *(const float4*)(src + j * 4);
    }
    __syncthreads();  // K ready
    f32x4 sacc = {0.f, 0.f, 0.f, 0.f};
    const int rr = wv * 16 + fh;
#pragma unroll
    for (int s = 0; s < 4; ++s) {
      const int off = rr * 256 + ((s * 64 + fg * 16) ^ ((rr & 7) << 4));
      const bf16x8 af = *(const bf16x8*)(Kl + off);
      sacc = __builtin_amdgcn_mfma_f32_16x16x32_bf16(af, qf[s], sacc, 0, 0, 0);
    }
    const int rowl = tt * 64 + wv * 16 + fg * 4;
#pragma unroll
    for (int j = 0; j < 4; ++j) {
      const int rw = rowl + j;
      if (rw < cnt) Sm[fh * 259 + rw] = sacc[j];
    }
  }

  // issue V tile 0 loads (fly during self-token + softmax)
  if (ntiles > 0) {
    const int r0g = n0 + 2 * vp;
    const int ra = min(r0g, LCACHE - 1);
    const int rb = min(r0g + 1, LCACHE - 1);
    const float* sa = vsrc + (size_t)ra * DH + vc * 16;
    const float* sb = vsrc + (size_t)rb * DH + vc * 16;
#pragma unroll
    for (int j = 0; j < 4; ++j) {
      kst[j] = *(const float4*)(sa + j * 4);
      kst[4 + j] = *(const float4*)(sb + j * 4);
    }
  }

  // ---- self token score ----
  if (has_self) {
    if (t < 128) {
      const int h = t >> 3;
      const int seg = t & 7;
      float ps = 0.f;
#pragma unroll
      for (int dd = 0; dd < 16; ++dd)
        ps += q_s[h * 132 + seg * 16 + dd] * kv_buf[(size_t)b * 256 + seg * 16 + dd];
      red[h * 8 + seg] = ps;
    }
    __syncthreads();
    if (t < H) {
      float s = 0.f;
#pragma unroll
      for (int seg = 0; seg < 8; ++seg) s += red[t * 8 + seg];
      Sm[t * 259 + cnt] = s;
    }
  }
  __syncthreads();

  // ---- softmax; produce bf16 P (zero-padded), selfp separate ----
  const int hX = t & 15;
  const int g = t >> 4;
  float mloc = -1e30f;
  for (int i = g; i < tot; i += 16) mloc = fmaxf(mloc, Sm[hX * 259 + i]);
  red[hX * 17 + g] = mloc;
  __syncthreads();
  if (t < H) {
    float mx = red[t * 17];
#pragma unroll
    for (int gg = 1; gg < 16; ++gg) mx = fmaxf(mx, red[t * 17 + gg]);
    mrow[t] = mx;
  }
  __syncthreads();
  const float mh = mrow[hX];
  float sloc = 0.f;
  const int ipad = ntiles * 64;
  const int iend = (ipad > tot) ? ipad : tot;
  unsigned short* Pu = (unsigned short*)P;
  for (int i = g; i < iend; i += 16) {
    if (i < cnt) {
      const float e = __expf(Sm[hX * 259 + i] - mh);
      Pu[hX * 264 + i] = bfr(e);
      sloc += e;
    } else {
      if (i < ipad) Pu[hX * 264 + i] = 0;
      if (has_self && i == cnt) {
        const float e = __expf(Sm[hX * 259 + cnt] - mh);
        selfp[hX] = e;
        sloc += e;
      }
    }
  }
  red[hX * 17 + g] = sloc;
  __syncthreads();
  if (t < H) {
    float ls = 0.f;
#pragma unroll
    for (int gg = 0; gg < 16; ++gg) ls += red[t * 17 + gg];
    part_m[((size_t)b * NSPLIT + sp) * H + t] = mrow[t];
    part_l[((size_t)b * NSPLIT + sp) * H + t] = ls;
  }
  __syncthreads();  // Sm/q_s dead -> region A free for Vt

  // ---- pass 2: PV via mfma(P, Vt) ----
  f32x4 oacc[2];
  oacc[0] = (f32x4){0.f, 0.f, 0.f, 0.f};
  oacc[1] = (f32x4){0.f, 0.f, 0.f, 0.f};
  unsigned* VtW = (unsigned*)Vt;
  for (int tt = 0; tt < ntiles; ++tt) {
    if (tt > 0) __syncthreads();
    // write V tile transposed: Vt[d][row], packed row pairs
#pragma unroll
    for (int j = 0; j < 4; ++j) {
      const float4 a = kst[j];
      const float4 b4 = kst[4 + j];
      const int d = vc * 16 + j * 4;
      VtW[(d + 0) * 44 + vp] = pkbf(a.x, b4.x);
      VtW[(d + 1) * 44 + vp] = pkbf(a.y, b4.y);
      VtW[(d + 2) * 44 + vp] = pkbf(a.z, b4.z);
      VtW[(d + 3) * 44 + vp] = pkbf(a.w, b4.w);
    }
    if (tt + 1 < ntiles) {
      const int r0g = n0 + (tt + 1) * 64 + 2 * vp;
      const int ra = min(r0g, LCACHE - 1);
      const int rb = min(r0g + 1, LCACHE - 1);
      const float* sa = vsrc + (size_t)ra * DH + vc * 16;
      const float* sb = vsrc + (size_t)rb * DH + vc * 16;
#pragma unroll
      for (int j = 0; j < 4; ++j) {
        kst[j] = *(const float4*)(sa + j * 4);
        kst[4 + j] = *(const float4*)(sb + j * 4);
      }
    }
    __syncthreads();
#pragma unroll
    for (int c2 = 0; c2 < 2; ++c2) {
      const bf16x8 pf = *(const bf16x8*)(P + fh * 528 + (tt * 64 + c2 * 32) * 2 + fg * 16);
#pragma unroll
      for (int dt = 0; dt < 2; ++dt) {
        const int d = wv * 32 + dt * 16 + fh;
        const bf16x8 vf = *(const bf16x8*)((char*)Vt + d * 176 + c2 * 64 + fg * 16);
        oacc[dt] = __builtin_amdgcn_mfma_f32_16x16x32_bf16(pf, vf, oacc[dt], 0, 0, 0);
      }
    }
  }

  // epilogue: self token + write partial out
  if (has_self) {
#pragma unroll
    for (int dt = 0; dt < 2; ++dt) {
      const int d = wv * 32 + dt * 16 + fh;
      const float vn = kv_buf[(size_t)b * 256 + 128 + d];
#pragma unroll
      for (int j = 0; j < 4; ++j) oacc[dt][j] = fmaf(selfp[fg * 4 + j], vn, oacc[dt][j]);
    }
  }
  float* po = part_out + (((size_t)b * NSPLIT + sp) * H) * DH;
#pragma unroll
  for (int dt = 0; dt < 2; ++dt) {
    const int d = wv * 32 + dt * 16 + fh;
#pragma unroll
    for (int j = 0; j < 4; ++j) po[(size_t)(fg * 4 + j) * DH + d] = oacc[dt][j];
  }
}

// ---------------- merge flash-decoding splits ----------------
template <int NSPLIT>
__global__ __launch_bounds__(256) void attn_combine(
    const float* __restrict__ part_out, const float* __restrict__ part_m,
    const float* __restrict__ part_l, float* __restrict__ ctx_buf) {
  const int b = blockIdx.x;
  const int dq = blockIdx.y;
  const int t = threadIdx.x;
  const int h = t >> 4;
  const int d = dq * 32 + (t & 15) * 2;
  float M = -1e30f;
#pragma unroll
  for (int sp = 0; sp < NSPLIT; ++sp)
    M = fmaxf(M, part_m[((size_t)b * NSPLIT + sp) * H + h]);
  float L = 0.f, o0 = 0.f, o1 = 0.f;
#pragma unroll
  for (int sp = 0; sp < NSPLIT; ++sp) {
    const float m = part_m[((size_t)b * NSPLIT + sp) * H + h];
    if (m < -1e29f) continue;
    const float w = __expf(m - M);
    L += w * part_l[((size_t)b * NSPLIT + sp) * H + h];
    const float2 a = *(const float2*)(part_out + (((size_t)b * NSPLIT + sp) * H + h) * DH + d);
    o0 = fmaf(w, a.x, o0);
    o1 = fmaf(w, a.y, o1);
  }
  const float inv = 1.f / L;
  float* dst = ctx_buf + (size_t)b * HID + h * DH + d;
  dst[0] = o0 * inv;
  dst[1] = o1 * inv;
}

extern "C" void kernel_launch(void* const* d_in, const int* in_sizes, int n_in,
                              void* d_out, int out_size, void* d_ws, size_t ws_size,
                              hipStream_t stream) {
  const float* hidden      = (const float*)d_in[0];
  const float* key_cache   = (const float*)d_in[1];
  const float* value_cache = (const float*)d_in[2];
  const float* Wq  = (const float*)d_in[3];
  const float* bq  = (const float*)d_in[4];
  const float* Wkv = (const float*)d_in[5];
  const float* bkv = (const float*)d_in[6];
  const float* Wo  = (const float*)d_in[7];
  const float* bo  = (const float*)d_in[8];
  const int*   lens = (const int*)d_in[9];
  float* out = (float*)d_out;

  float* ws = (float*)d_ws;
  float* part1    = ws;                                    // 16*64*2304
  float* q_buf    = part1 + (size_t)NKS * 64 * 2304;       // 64*2048
  float* kv_buf   = q_buf + (size_t)64 * HID;              // 64*256
  float* part_out = kv_buf + (size_t)64 * 256;             // 64*NS*H*DH
  float* part_m   = part_out + (size_t)64 * NS * H * DH;   // 64*NS*H
  float* part_l   = part_m + (size_t)64 * NS * H;          // 64*NS*H
  float* ctx_buf  = part_l + (size_t)64 * NS * H;          // 64*2048
  float* part2    = ctx_buf + (size_t)64 * HID;            // 16*64*2048
  float* At       = part2 + (size_t)NKS * 64 * 2048;       // 2048*64
  float* ctxT     = At + (size_t)HID * 64;                 // 2048*64

  transpose64<<<dim3(32), dim3(256), 0, stream>>>(hidden, At);
  proj_v2<<<dim3(18, NKS), dim3(256), 0, stream>>>(At, Wq, Wkv, part1, 2048, 256);
  proj_combine<<<dim3(144), dim3(256), 0, stream>>>(part1, bq, bkv, q_buf, kv_buf, 2048, 256);
  attn_mfma<NS><<<dim3(NS, NB), dim3(256), 0, stream>>>(q_buf, kv_buf, key_cache, value_cache,
                                                        lens, part_out, part_m, part_l);
  attn_combine<NS><<<dim3(NB, 4), dim3(256), 0, stream>>>(part_out, part_m, part_l, ctx_buf);
  transpose64<<<dim3(32), dim3(256), 0, stream>>>(ctx_buf, ctxT);
  proj_v2<<<dim3(16, NKS), dim3(256), 0, stream>>>(ctxT, Wo, Wo, part2, 2048, 0);
  proj_combine<<<dim3(128), dim3(256), 0, stream>>>(part2, bo, bo, out, nullptr, 2048, 0);
}

// Round 4
// 101.327 us; speedup vs baseline: 2.0440x; 1.0621x over previous
//
#include <hip/hip_runtime.h>
#include <hip/hip_bf16.h>
#include <math.h>

#define H 16
#define DH 128
#define HID 2048
#define NB 64
#define LCACHE 4096
#define NS 16
#define NKS 16
#define SCALE 0.08838834764831845f

typedef __attribute__((ext_vector_type(8))) short bf16x8;
typedef __attribute__((ext_vector_type(4))) float f32x4;

static __device__ inline unsigned short bfr(float x) {
  union { __hip_bfloat16 b; unsigned short u; } c;
  c.b = __float2bfloat16(x);
  return c.u;
}
static __device__ inline unsigned pkbf(float lo, float hi) {
  return (unsigned)bfr(lo) | ((unsigned)bfr(hi) << 16);
}
union BFU { unsigned u[4]; bf16x8 v; };

// ---------------- transpose A[64][2048] -> At[2048][64] ----------------
__global__ __launch_bounds__(256) void transpose64(const float* __restrict__ A,
                                                   float* __restrict__ At) {
  __shared__ float tile[64 * 65];
  const int k0 = blockIdx.x * 64;
  for (int idx = threadIdx.x; idx < 4096; idx += 256) {
    const int m = idx >> 6, c = idx & 63;
    tile[c * 65 + m] = A[(size_t)m * HID + k0 + c];
  }
  __syncthreads();
  for (int idx = threadIdx.x; idx < 4096; idx += 256) {
    const int c = idx >> 6, m = idx & 63;
    At[(size_t)(k0 + c) * 64 + m] = tile[c * 65 + m];
  }
}

// ---------------- projection: outer-product, W streamed once ----------------
__global__ __launch_bounds__(256, 4) void proj_v2(
    const float* __restrict__ At, const float* __restrict__ W1, const float* __restrict__ W2,
    float* __restrict__ part, int NC1, int NC2) {
  const int NC = NC1 + NC2;
  const int n0 = blockIdx.x * 128;
  const int k0 = blockIdx.y * 128;
  __shared__ float Asub[128 * 68];
  const int t = threadIdx.x;
#pragma unroll
  for (int j = 0; j < 8; ++j) {
    const int f = t * 4 + j * 1024;
    const int k = f >> 6, m = f & 63;
    *(float4*)&Asub[k * 68 + m] = *(const float4*)(At + (size_t)(k0 + k) * 64 + m);
  }
  __syncthreads();
  const int m0 = (t & 15) * 4;
  const int ng = (t >> 4) * 8;
  const float* Wp;
  int ldw, wc;
  if (n0 + ng < NC1) { Wp = W1; ldw = NC1; wc = n0 + ng; }
  else               { Wp = W2; ldw = NC2; wc = n0 + ng - NC1; }
  float acc[4][8];
#pragma unroll
  for (int i = 0; i < 4; ++i)
#pragma unroll
    for (int j = 0; j < 8; ++j) acc[i][j] = 0.f;
#pragma unroll 4
  for (int k = 0; k < 128; ++k) {
    const float4 a4 = *(const float4*)&Asub[k * 68 + m0];
    const float* wrow = Wp + (size_t)(k0 + k) * ldw + wc;
    const float4 w0 = *(const float4*)(wrow);
    const float4 w1 = *(const float4*)(wrow + 4);
    const float av[4] = {a4.x, a4.y, a4.z, a4.w};
    const float wv[8] = {w0.x, w0.y, w0.z, w0.w, w1.x, w1.y, w1.z, w1.w};
#pragma unroll
    for (int i = 0; i < 4; ++i)
#pragma unroll
      for (int j = 0; j < 8; ++j) acc[i][j] = fmaf(av[i], wv[j], acc[i][j]);
  }
#pragma unroll
  for (int i = 0; i < 4; ++i) {
    float4 o1, o2;
    o1.x = acc[i][0]; o1.y = acc[i][1]; o1.z = acc[i][2]; o1.w = acc[i][3];
    o2.x = acc[i][4]; o2.y = acc[i][5]; o2.z = acc[i][6]; o2.w = acc[i][7];
    float* dst = part + ((size_t)blockIdx.y * 64 + m0 + i) * NC + n0 + ng;
    *(float4*)dst = o1;
    *(float4*)(dst + 4) = o2;
  }
}

__global__ __launch_bounds__(256) void proj_combine(
    const float* __restrict__ part, const float* __restrict__ b1, const float* __restrict__ b2,
    float* __restrict__ out1, float* __restrict__ out2, int NC1, int NC2, float scale1) {
  const int NC = NC1 + NC2;
  const int f = (blockIdx.x * 256 + threadIdx.x) * 4;
  if (f >= 64 * NC) return;
  const int row = f / NC;
  const int c = f - row * NC;
  float4 s = *(const float4*)(part + (size_t)row * NC + c);
#pragma unroll
  for (int sp = 1; sp < NKS; ++sp) {
    const float4 p = *(const float4*)(part + ((size_t)sp * 64 + row) * NC + c);
    s.x += p.x; s.y += p.y; s.z += p.z; s.w += p.w;
  }
  if (c < NC1) {
    const float4 bb = *(const float4*)(b1 + c);
    s.x = (s.x + bb.x) * scale1; s.y = (s.y + bb.y) * scale1;
    s.z = (s.z + bb.z) * scale1; s.w = (s.w + bb.w) * scale1;
    *(float4*)(out1 + (size_t)row * NC1 + c) = s;
  } else {
    const int cc = c - NC1;
    const float4 bb = *(const float4*)(b2 + cc);
    s.x += bb.x; s.y += bb.y; s.z += bb.z; s.w += bb.w;
    *(float4*)(out2 + (size_t)row * NC2 + cc) = s;
  }
}

// ---------------- single-pass MFMA flash-decoding attention ----------------
template <int NSPLIT>
__global__ __launch_bounds__(256, 3) void attn_fused(
    const float* __restrict__ q_buf, const float* __restrict__ kv_buf,
    const float* __restrict__ key_cache, const float* __restrict__ value_cache,
    const int* __restrict__ lens,
    float* __restrict__ part_out, float* __restrict__ part_m, float* __restrict__ part_l) {
  const int b = blockIdx.y;
  const int sp = blockIdx.x;
  const int ctx = lens[b];
  const int n0 = (ctx * sp) / NSPLIT;
  const int n1 = (ctx * (sp + 1)) / NSPLIT;
  const int cnt = n1 - n0;
  const bool has_self = (sp == NSPLIT - 1);
  const int t = threadIdx.x;
  if (cnt == 0 && !has_self) {
    if (t < H) {
      part_m[((size_t)b * NSPLIT + sp) * H + t] = -1e30f;
      part_l[((size_t)b * NSPLIT + sp) * H + t] = 0.f;
    }
    return;
  }
  __shared__ __align__(16) char sV[22528];            // Vt u32[128][44]; prologue alias q_s f32[16][132]
  __shared__ __align__(16) char sK[16384];            // K bf16 [64][128] swizzled
  __shared__ __align__(16) unsigned Pbuf[16 * 36];    // P bf16 pairs
  __shared__ __align__(16) float red1[64];
  __shared__ __align__(16) float red2[64];
  __shared__ __align__(16) float mrun[2][16];
  __shared__ __align__(16) float lrun[2][16];
  __shared__ __align__(16) float sself[16];
  __shared__ float sred[128];

  float* q_s = (float*)sV;
  unsigned* VtW = (unsigned*)sV;
  unsigned* Kl32 = (unsigned*)sK;

  // stage q (already scaled by proj_combine)
  for (int idx = t; idx < HID; idx += 256)
    q_s[(idx >> 7) * 132 + (idx & 127)] = q_buf[(size_t)b * HID + idx];
  if (t < 16) { mrun[0][t] = -1e30f; lrun[0][t] = 0.f; }
  __syncthreads();

  const int lane = t & 63;
  const int wv = t >> 6;
  const int fh = lane & 15;
  const int fg = lane >> 4;
  const int vp = t & 31;
  const int vc = t >> 5;
  const int ntiles = (cnt + 63) >> 6;
  const float* ksrc = key_cache + (size_t)b * LCACHE * DH;
  const float* vsrc = value_cache + (size_t)b * LCACHE * DH;

  // q B-frags
  bf16x8 qf[4];
#pragma unroll
  for (int s = 0; s < 4; ++s) {
    const float4 qa = *(const float4*)&q_s[fh * 132 + s * 32 + fg * 8];
    const float4 qb = *(const float4*)&q_s[fh * 132 + s * 32 + fg * 8 + 4];
    BFU u;
    u.u[0] = pkbf(qa.x, qa.y); u.u[1] = pkbf(qa.z, qa.w);
    u.u[2] = pkbf(qb.x, qb.y); u.u[3] = pkbf(qb.z, qb.w);
    qf[s] = u.v;
  }
  // self-token partial scores
  if (has_self && t < 128) {
    const int h = t >> 3, seg = t & 7;
    float ps = 0.f;
#pragma unroll
    for (int dd = 0; dd < 16; ++dd)
      ps += q_s[h * 132 + seg * 16 + dd] * kv_buf[(size_t)b * 256 + seg * 16 + dd];
    sred[t] = ps;
  }

  // prefetch tile 0
  float4 kst[8], vst[8];
  if (ntiles > 0) {
    const int tb = n0 * DH;
#pragma unroll
    for (int j = 0; j < 8; ++j) {
      const int off = min(tb + j * 1024 + t * 4, LCACHE * DH - 4);
      kst[j] = *(const float4*)(ksrc + off);
    }
    const int r0 = n0 + 2 * vp;
    const float* sa = vsrc + (size_t)min(r0, LCACHE - 1) * DH + vc * 16;
    const float* sb = vsrc + (size_t)min(r0 + 1, LCACHE - 1) * DH + vc * 16;
#pragma unroll
    for (int j = 0; j < 4; ++j) {
      vst[j] = *(const float4*)(sa + j * 4);
      vst[4 + j] = *(const float4*)(sb + j * 4);
    }
  }
  __syncthreads();  // q_s dead; sred ready

  if (has_self && t < 16) {
    float s = 0.f;
#pragma unroll
    for (int seg = 0; seg < 8; ++seg) s += sred[t * 8 + seg];
    sself[t] = s;
  }

  f32x4 oacc[2];
  oacc[0] = (f32x4){0.f, 0.f, 0.f, 0.f};
  oacc[1] = (f32x4){0.f, 0.f, 0.f, 0.f};
  int par = 0;

  for (int tt = 0; tt < ntiles; ++tt) {
    if (tt > 0) __syncthreads();  // A: prev PV reads done
    // stage K (flat-coalesced ownership, swizzled LDS)
#pragma unroll
    for (int j = 0; j < 8; ++j) {
      const int row = j * 8 + (t >> 5);
      const int byteo = ((t & 31) * 8) ^ ((row & 7) << 4);
      const int w0 = row * 64 + (byteo >> 2);
      Kl32[w0] = pkbf(kst[j].x, kst[j].y);
      Kl32[w0 + 1] = pkbf(kst[j].z, kst[j].w);
    }
    // stage Vt (transposed, row-pair packed)
#pragma unroll
    for (int j = 0; j < 4; ++j) {
      const float4 a = vst[j];
      const float4 b4 = vst[4 + j];
      const int d = vc * 16 + j * 4;
      VtW[(d + 0) * 44 + vp] = pkbf(a.x, b4.x);
      VtW[(d + 1) * 44 + vp] = pkbf(a.y, b4.y);
      VtW[(d + 2) * 44 + vp] = pkbf(a.z, b4.z);
      VtW[(d + 3) * 44 + vp] = pkbf(a.w, b4.w);
    }
    // prefetch next tile
    if (tt + 1 < ntiles) {
      const int tb = (n0 + (tt + 1) * 64) * DH;
#pragma unroll
      for (int j = 0; j < 8; ++j) {
        const int off = min(tb + j * 1024 + t * 4, LCACHE * DH - 4);
        kst[j] = *(const float4*)(ksrc + off);
      }
      const int r0 = n0 + (tt + 1) * 64 + 2 * vp;
      const float* sa = vsrc + (size_t)min(r0, LCACHE - 1) * DH + vc * 16;
      const float* sb = vsrc + (size_t)min(r0 + 1, LCACHE - 1) * DH + vc * 16;
#pragma unroll
      for (int j = 0; j < 4; ++j) {
        vst[j] = *(const float4*)(sa + j * 4);
        vst[4 + j] = *(const float4*)(sb + j * 4);
      }
    }
    __syncthreads();  // B: LDS tiles ready

    // QK^T
    f32x4 sacc = {0.f, 0.f, 0.f, 0.f};
    const int rr = wv * 16 + fh;
#pragma unroll
    for (int s = 0; s < 4; ++s) {
      const int off = rr * 256 + ((s * 64 + fg * 16) ^ ((rr & 7) << 4));
      const bf16x8 af = *(const bf16x8*)(sK + off);
      sacc = __builtin_amdgcn_mfma_f32_16x16x32_bf16(af, qf[s], sacc, 0, 0, 0);
    }
    // mask invalid rows
    const int rloc = wv * 16 + fg * 4;
    const int lim = cnt - tt * 64;
    float s0 = (rloc + 0 < lim) ? sacc[0] : -1e30f;
    float s1 = (rloc + 1 < lim) ? sacc[1] : -1e30f;
    float s2 = (rloc + 2 < lim) ? sacc[2] : -1e30f;
    float s3 = (rloc + 3 < lim) ? sacc[3] : -1e30f;
    // per-wave per-head max
    float ml = fmaxf(fmaxf(s0, s1), fmaxf(s2, s3));
    ml = fmaxf(ml, __shfl_xor(ml, 16, 64));
    ml = fmaxf(ml, __shfl_xor(ml, 32, 64));
    if (fg == 0) red1[wv * 16 + fh] = ml;
    __syncthreads();  // C

    // tile max / new running max
    const float4 r0v = *(const float4*)&red1[0 + fg * 4];
    const float4 r1v = *(const float4*)&red1[16 + fg * 4];
    const float4 r2v = *(const float4*)&red1[32 + fg * 4];
    const float4 r3v = *(const float4*)&red1[48 + fg * 4];
    float mt[4];
    mt[0] = fmaxf(fmaxf(r0v.x, r1v.x), fmaxf(r2v.x, r3v.x));
    mt[1] = fmaxf(fmaxf(r0v.y, r1v.y), fmaxf(r2v.y, r3v.y));
    mt[2] = fmaxf(fmaxf(r0v.z, r1v.z), fmaxf(r2v.z, r3v.z));
    mt[3] = fmaxf(fmaxf(r0v.w, r1v.w), fmaxf(r2v.w, r3v.w));
    float mtf = fmaxf(fmaxf(red1[fh], red1[16 + fh]), fmaxf(red1[32 + fh], red1[48 + fh]));
    const float4 mp4 = *(const float4*)&mrun[par][fg * 4];
    const float mpf = mrun[par][fh];
    const float mnf = fmaxf(mtf, mpf);
    // probabilities (head fh)
    const float p0 = __expf(s0 - mnf);
    const float p1 = __expf(s1 - mnf);
    const float p2 = __expf(s2 - mnf);
    const float p3 = __expf(s3 - mnf);
    // rescale O accumulators (heads fg*4+j)
    {
      const float mpj[4] = {mp4.x, mp4.y, mp4.z, mp4.w};
#pragma unroll
      for (int j = 0; j < 4; ++j) {
        const float mn = fmaxf(mt[j], mpj[j]);
        const float rf = __expf(mpj[j] - mn);
        oacc[0][j] *= rf;
        oacc[1][j] *= rf;
      }
    }
    // row-sum
    float sl = p0 + p1 + p2 + p3;
    sl += __shfl_xor(sl, 16, 64);
    sl += __shfl_xor(sl, 32, 64);
    if (fg == 0) red2[wv * 16 + fh] = sl;
    // P write (bf16 pairs)
    Pbuf[fh * 36 + wv * 8 + fg * 2] = pkbf(p0, p1);
    Pbuf[fh * 36 + wv * 8 + fg * 2 + 1] = pkbf(p2, p3);
    if (t < 16) mrun[par ^ 1][t] = mnf;
    __syncthreads();  // E: P + red2 + mrun ready

    if (t < 16) {
      const float lsum = red2[t] + red2[16 + t] + red2[32 + t] + red2[48 + t];
      const float mpt = mrun[par][t];
      const float mnt = mrun[par ^ 1][t];
      lrun[par ^ 1][t] = lrun[par][t] * __expf(mpt - mnt) + lsum;
    }
    // PV
#pragma unroll
    for (int c2 = 0; c2 < 2; ++c2) {
      const bf16x8 pf = *(const bf16x8*)&Pbuf[fh * 36 + c2 * 16 + fg * 4];
#pragma unroll
      for (int dt = 0; dt < 2; ++dt) {
        const int d = wv * 32 + dt * 16 + fh;
        const bf16x8 vf = *(const bf16x8*)&VtW[d * 44 + c2 * 16 + fg * 4];
        oacc[dt] = __builtin_amdgcn_mfma_f32_16x16x32_bf16(pf, vf, oacc[dt], 0, 0, 0);
      }
    }
    par ^= 1;
  }
  __syncthreads();  // F: final mrun/lrun visible

  const int parF = par;
  if (has_self) {
    const float4 mp4 = *(const float4*)&mrun[parF][fg * 4];
    const float4 ss4 = *(const float4*)&sself[fg * 4];
    const float vn0 = kv_buf[(size_t)b * 256 + 128 + wv * 32 + fh];
    const float vn1 = kv_buf[(size_t)b * 256 + 128 + wv * 32 + 16 + fh];
    const float mpj[4] = {mp4.x, mp4.y, mp4.z, mp4.w};
    const float ssj[4] = {ss4.x, ss4.y, ss4.z, ss4.w};
#pragma unroll
    for (int j = 0; j < 4; ++j) {
      const float mn = fmaxf(mpj[j], ssj[j]);
      const float rf = __expf(mpj[j] - mn);
      const float ps = __expf(ssj[j] - mn);
      oacc[0][j] = oacc[0][j] * rf + ps * vn0;
      oacc[1][j] = oacc[1][j] * rf + ps * vn1;
    }
    if (t < 16) {
      const float mp = mrun[parF][t], ss = sself[t];
      const float mn = fmaxf(mp, ss);
      part_m[((size_t)b * NSPLIT + sp) * H + t] = mn;
      part_l[((size_t)b * NSPLIT + sp) * H + t] =
          lrun[parF][t] * __expf(mp - mn) + __expf(ss - mn);
    }
  } else {
    if (t < 16) {
      part_m[((size_t)b * NSPLIT + sp) * H + t] = mrun[parF][t];
      part_l[((size_t)b * NSPLIT + sp) * H + t] = lrun[parF][t];
    }
  }
  float* po = part_out + ((size_t)b * NSPLIT + sp) * H * DH;
#pragma unroll
  for (int dt = 0; dt < 2; ++dt) {
    const int d = wv * 32 + dt * 16 + fh;
#pragma unroll
    for (int j = 0; j < 4; ++j) po[(size_t)(fg * 4 + j) * DH + d] = oacc[dt][j];
  }
}

// ---------------- merge splits, write ctx TRANSPOSED [2048][64] ----------------
__global__ __launch_bounds__(256) void attn_combineT(
    const float* __restrict__ part_out, const float* __restrict__ part_m,
    const float* __restrict__ part_l, float* __restrict__ ctxT) {
  const int h = blockIdx.x;
  const int d0 = blockIdx.y * 32 + (threadIdx.x >> 6) * 8;
  const int b = threadIdx.x & 63;
  float M = -1e30f;
#pragma unroll
  for (int sp = 0; sp < NS; ++sp)
    M = fmaxf(M, part_m[((size_t)b * NS + sp) * H + h]);
  float L = 0.f;
  float o[8];
#pragma unroll
  for (int i = 0; i < 8; ++i) o[i] = 0.f;
#pragma unroll
  for (int sp = 0; sp < NS; ++sp) {
    const float m = part_m[((size_t)b * NS + sp) * H + h];
    if (m < -1e29f) continue;
    const float w = __expf(m - M);
    L += w * part_l[((size_t)b * NS + sp) * H + h];
    const float* src = part_out + (((size_t)b * NS + sp) * H + h) * DH + d0;
    const float4 a = *(const float4*)src;
    const float4 c = *(const float4*)(src + 4);
    o[0] = fmaf(w, a.x, o[0]); o[1] = fmaf(w, a.y, o[1]);
    o[2] = fmaf(w, a.z, o[2]); o[3] = fmaf(w, a.w, o[3]);
    o[4] = fmaf(w, c.x, o[4]); o[5] = fmaf(w, c.y, o[5]);
    o[6] = fmaf(w, c.z, o[6]); o[7] = fmaf(w, c.w, o[7]);
  }
  const float inv = 1.f / L;
#pragma unroll
  for (int i = 0; i < 8; ++i)
    ctxT[(size_t)(h * DH + d0 + i) * 64 + b] = o[i] * inv;
}

extern "C" void kernel_launch(void* const* d_in, const int* in_sizes, int n_in,
                              void* d_out, int out_size, void* d_ws, size_t ws_size,
                              hipStream_t stream) {
  const float* hidden      = (const float*)d_in[0];
  const float* key_cache   = (const float*)d_in[1];
  const float* value_cache = (const float*)d_in[2];
  const float* Wq  = (const float*)d_in[3];
  const float* bq  = (const float*)d_in[4];
  const float* Wkv = (const float*)d_in[5];
  const float* bkv = (const float*)d_in[6];
  const float* Wo  = (const float*)d_in[7];
  const float* bo  = (const float*)d_in[8];
  const int*   lens = (const int*)d_in[9];
  float* out = (float*)d_out;

  float* ws = (float*)d_ws;
  float* part1    = ws;                                    // 16*64*2304
  float* q_buf    = part1 + (size_t)NKS * 64 * 2304;       // 64*2048 (pre-scaled)
  float* kv_buf   = q_buf + (size_t)64 * HID;              // 64*256
  float* part_out = kv_buf + (size_t)64 * 256;             // 64*NS*H*DH
  float* part_m   = part_out + (size_t)64 * NS * H * DH;   // 64*NS*H
  float* part_l   = part_m + (size_t)64 * NS * H;          // 64*NS*H
  float* ctxT     = part_l + (size_t)64 * NS * H;          // 2048*64
  float* part2    = ctxT + (size_t)HID * 64;               // 16*64*2048
  float* At       = part2 + (size_t)NKS * 64 * 2048;       // 2048*64

  transpose64<<<dim3(32), dim3(256), 0, stream>>>(hidden, At);
  proj_v2<<<dim3(18, NKS), dim3(256), 0, stream>>>(At, Wq, Wkv, part1, 2048, 256);
  proj_combine<<<dim3(144), dim3(256), 0, stream>>>(part1, bq, bkv, q_buf, kv_buf, 2048, 256, SCALE);
  attn_fused<NS><<<dim3(NS, NB), dim3(256), 0, stream>>>(q_buf, kv_buf, key_cache, value_cache,
                                                         lens, part_out, part_m, part_l);
  attn_combineT<<<dim3(H, 4), dim3(256), 0, stream>>>(part_out, part_m, part_l, ctxT);
  proj_v2<<<dim3(16, NKS), dim3(256), 0, stream>>>(ctxT, Wo, Wo, part2, 2048, 0);
  proj_combine<<<dim3(128), dim3(256), 0, stream>>>(part2, bo, bo, out, nullptr, 2048, 0, 1.0f);
}